// Round 10
// baseline (266.944 us; speedup 1.0000x reference)
//
#include <hip/hip_runtime.h>
#include <hip/hip_fp16.h>

typedef _Float16 f16;
typedef _Float16 f16x8 __attribute__((ext_vector_type(8)));
typedef float f32x4 __attribute__((ext_vector_type(4)));

constexpr int C = 128;     // channels
constexpr int V = 65536;   // voxels
constexpr int PTS = 64;    // points per MFMA tile
constexpr int BLOCK = 256; // 4 waves
constexpr int BKT = 64;    // bucket capacity per voxel (P(overflow) ~ 1e-26)

union U16 { uint4 u; f16x8 h; };

// -------------------------------------------------------------------------
// Kernel 0: zero the counters (rocclr's small fill kernel is latency-bound).
// -------------------------------------------------------------------------
__global__ void zero_cnt(int4* __restrict__ cnt) {
    const int t = blockIdx.x * blockDim.x + threadIdx.x;
    cnt[t] = make_int4(0, 0, 0, 0);
}

// -------------------------------------------------------------------------
// Kernel 1: bucket scatter — fixed-stride CSR, no scan needed.
// -------------------------------------------------------------------------
__global__ void bucket_scatter(const int* __restrict__ idx, int* __restrict__ cnt,
                               int* __restrict__ bucket, int n) {
    const int t = blockIdx.x * blockDim.x + threadIdx.x;
    if (t < n) {
        const int v = idx[t];
        const int slot = atomicAdd(&cnt[v], 1);
        if (slot < BKT) bucket[(v << 6) + slot] = t;
    }
}

// -------------------------------------------------------------------------
// Kernel 2: pooling — one wave per voxel, fp32 accumulate (4-deep ILP),
// f16 mean store.
// -------------------------------------------------------------------------
__global__ void __launch_bounds__(256)
pool_bucket(const float* __restrict__ feats, const int* __restrict__ bucket,
            const int* __restrict__ cnt, __half* __restrict__ pooled) {
    const int v = blockIdx.x * 4 + (threadIdx.x >> 6);
    const int lane = threadIdx.x & 63;
    const int e = min(cnt[v], BKT);
    const int* b = bucket + (v << 6);
    float ax = 0.f, ay = 0.f, bx = 0.f, by = 0.f;
    float cx = 0.f, cy = 0.f, dx = 0.f, dy = 0.f;
    int j = 0;
    for (; j + 4 <= e; j += 4) {
        const int p0 = b[j], p1 = b[j + 1], p2 = b[j + 2], p3 = b[j + 3];
        const float2 f0 = *reinterpret_cast<const float2*>(feats + (size_t)p0 * C + lane * 2);
        const float2 f1 = *reinterpret_cast<const float2*>(feats + (size_t)p1 * C + lane * 2);
        const float2 f2 = *reinterpret_cast<const float2*>(feats + (size_t)p2 * C + lane * 2);
        const float2 f3 = *reinterpret_cast<const float2*>(feats + (size_t)p3 * C + lane * 2);
        ax += f0.x; ay += f0.y; bx += f1.x; by += f1.y;
        cx += f2.x; cy += f2.y; dx += f3.x; dy += f3.y;
    }
    for (; j < e; ++j) {
        const int p0 = b[j];
        const float2 f0 = *reinterpret_cast<const float2*>(feats + (size_t)p0 * C + lane * 2);
        ax += f0.x; ay += f0.y;
    }
    const float rc = e ? 1.0f / (float)e : 0.f;
    *reinterpret_cast<__half2*>(pooled + (size_t)v * C + lane * 2) =
        __floats2half2_rn((ax + bx + cx + dx) * rc, (ay + by + cy + dy) * rc);
}

// -------------------------------------------------------------------------
// Kernel 3: fused gather + 2-layer MLP via f16 MFMA (16x16x32).
//   os  = feats - pooled_mean[idx]     (staged in LDS, f16, swizzled)
//   h   = relu(os @ W1 + b1) * feats   (h OVERWRITES the os buffer)
//   out = relu(h @ W2 + b2)            (fp32 coalesced-row store)
// LDS = 32 KB, natural VGPR (no min-waves: forcing it spills, R6/R8).
// T14 async-STAGE: tile t+1's feats+pooled loads issue right after bar1 and
// fly under tile t's MFMA phases; idx is prefetched TWO tiles ahead so the
// pooled gather address is register-resident when the load issues.
// -------------------------------------------------------------------------
__global__ void __launch_bounds__(BLOCK)
mlp_mfma(const float* __restrict__ feats,
         const float* __restrict__ W1g,
         const float* __restrict__ b1g,
         const float* __restrict__ W2g,
         const float* __restrict__ b2g,
         const int* __restrict__ idx,
         const __half* __restrict__ pooled,
         float* __restrict__ out,
         int n) {
    __shared__ f16 osh_lds[PTS * C];  // 16 KB: holds os, then h (XOR-swizzled)
    __shared__ f16 f_lds[PTS * C];    // 16 KB

    const int t = threadIdx.x;
    const int lane = t & 63;
    const int wv = t >> 6;
    const int l15 = lane & 15;
    const int lg = lane >> 4;
    const int chBase = 32 * wv;

    // Weight fragments in registers (B-fragment: col = lane&15, k = (lane>>4)*8+j)
    const int ch0 = chBase + l15;
    const int ch1 = chBase + 16 + l15;
    f16x8 w1f[2][4], w2f[2][4];
#pragma unroll
    for (int m = 0; m < 2; ++m) {
        const int ch = (m == 0) ? ch0 : ch1;
#pragma unroll
        for (int s = 0; s < 4; ++s) {
            f16x8 a, b;
#pragma unroll
            for (int j = 0; j < 8; ++j) {
                const int k = s * 32 + lg * 8 + j;
                a[j] = (f16)W1g[k * C + ch];
                b[j] = (f16)W2g[k * C + ch];
            }
            w1f[m][s] = a;
            w2f[m][s] = b;
        }
    }
    const float b1v[2] = {b1g[ch0], b1g[ch1]};
    const float b2v[2] = {b2g[ch0], b2g[ch1]};

    const int sp = t >> 2;
    const int sc = (t & 3) * 32;
    const long long step = (long long)gridDim.x * PTS;

    // ---- Prologue: load tile 0 data; prefetch idx for tile 1 -------------
    union { uint4 u[8]; float f[32]; float4 v[8]; } ff;
    union { uint4 u[4]; __half h[32]; } pl;
    int vnx;  // voxel id for the NEXT tile's point
    {
        const long long p = (long long)blockIdx.x * PTS + sp;
        if (p < n) {
            const int v = idx[p];
#pragma unroll
            for (int j = 0; j < 8; ++j)
                ff.v[j] = *reinterpret_cast<const float4*>(feats + (size_t)p * C + sc + j * 4);
            const uint4* pp = reinterpret_cast<const uint4*>(pooled + (size_t)v * C + sc);
#pragma unroll
            for (int j = 0; j < 4; ++j) pl.u[j] = pp[j];
        } else {
#pragma unroll
            for (int j = 0; j < 8; ++j) ff.u[j] = make_uint4(0, 0, 0, 0);
#pragma unroll
            for (int j = 0; j < 4; ++j) pl.u[j] = make_uint4(0, 0, 0, 0);
        }
        const long long p2 = p + step;
        vnx = (p2 < n) ? idx[p2] : -1;
    }

    for (long long base = (long long)blockIdx.x * PTS; base < n;
         base += step) {
        // ---- Stage os (= f - mean) and f into LDS (from prefetched regs) --
        {
            union { uint4 u[4]; f16 h[32]; } osv, fvh;
#pragma unroll
            for (int j = 0; j < 32; ++j) {
                const float fj = ff.f[j];
                const float mj = __half2float(pl.h[j]);
                osv.h[j] = (f16)(fj - mj);
                fvh.h[j] = (f16)fj;
            }
#pragma unroll
            for (int u = 0; u < 4; ++u) {
                const int byte = (sp * 256 + (sc + u * 8) * 2) ^ ((sp & 7) << 4);
                *reinterpret_cast<uint4*>(reinterpret_cast<char*>(osh_lds) + byte) = osv.u[u];
                *reinterpret_cast<uint4*>(reinterpret_cast<char*>(f_lds) + byte) = fvh.u[u];
            }
        }
        __syncthreads();  // bar1: os/f staged

        // ---- Issue next tile's loads (hidden under L1/h/L2 phases) -------
        {
            const long long p = base + step + sp;
            if (p < n) {
#pragma unroll
                for (int j = 0; j < 8; ++j)
                    ff.v[j] = *reinterpret_cast<const float4*>(feats + (size_t)p * C + sc + j * 4);
            } else {
#pragma unroll
                for (int j = 0; j < 8; ++j) ff.u[j] = make_uint4(0, 0, 0, 0);
            }
            if (vnx >= 0) {
                const uint4* pp = reinterpret_cast<const uint4*>(pooled + (size_t)vnx * C + sc);
#pragma unroll
                for (int j = 0; j < 4; ++j) pl.u[j] = pp[j];
            } else {
#pragma unroll
                for (int j = 0; j < 4; ++j) pl.u[j] = make_uint4(0, 0, 0, 0);
            }
            const long long p2 = base + 2 * step + sp;
            vnx = (p2 < n) ? idx[p2] : -1;
        }

        // ---- Layer 1: acc = os @ W1 + b1 --------------------------------
        f32x4 acc[2][4];
#pragma unroll
        for (int m = 0; m < 2; ++m)
#pragma unroll
            for (int q = 0; q < 4; ++q)
                acc[m][q] = (f32x4){b1v[m], b1v[m], b1v[m], b1v[m]};

#pragma unroll
        for (int s = 0; s < 4; ++s) {
            f16x8 af[4];
#pragma unroll
            for (int q = 0; q < 4; ++q) {
                const int p = q * 16 + l15;
                const int byte = (p * 256 + (s * 32 + lg * 8) * 2) ^ ((p & 7) << 4);
                U16 tmp;
                tmp.u = *reinterpret_cast<const uint4*>(reinterpret_cast<const char*>(osh_lds) + byte);
                af[q] = tmp.h;
            }
#pragma unroll
            for (int m = 0; m < 2; ++m)
#pragma unroll
                for (int q = 0; q < 4; ++q)
                    acc[m][q] = __builtin_amdgcn_mfma_f32_16x16x32_f16(af[q], w1f[m][s], acc[m][q], 0, 0, 0);
        }
        __syncthreads();  // bar2: all os reads done -> safe to overwrite with h

        // ---- h = relu(acc) * f -> osh_lds (overwrite os) ----------------
        // C/D layout: col = lane&15 (channel), row = (lane>>4)*4 + reg (point)
#pragma unroll
        for (int m = 0; m < 2; ++m) {
            const int ch = chBase + m * 16 + l15;
#pragma unroll
            for (int q = 0; q < 4; ++q)
#pragma unroll
                for (int r = 0; r < 4; ++r) {
                    const int d = q * 16 + lg * 4 + r;
                    const int byte = (d * 256 + ch * 2) ^ ((d & 7) << 4);
                    const float fval = (float)*reinterpret_cast<const f16*>(
                        reinterpret_cast<const char*>(f_lds) + byte);
                    const float hv = fmaxf(acc[m][q][r], 0.f) * fval;
                    *reinterpret_cast<f16*>(reinterpret_cast<char*>(osh_lds) + byte) = (f16)hv;
                }
        }
        __syncthreads();  // bar3: h ready

        // ---- Layer 2: out = relu(h @ W2 + b2) ---------------------------
        f32x4 acc2[2][4];
#pragma unroll
        for (int m = 0; m < 2; ++m)
#pragma unroll
            for (int q = 0; q < 4; ++q)
                acc2[m][q] = (f32x4){b2v[m], b2v[m], b2v[m], b2v[m]};

#pragma unroll
        for (int s = 0; s < 4; ++s) {
            f16x8 af[4];
#pragma unroll
            for (int q = 0; q < 4; ++q) {
                const int p = q * 16 + l15;
                const int byte = (p * 256 + (s * 32 + lg * 8) * 2) ^ ((p & 7) << 4);
                U16 tmp;
                tmp.u = *reinterpret_cast<const uint4*>(reinterpret_cast<const char*>(osh_lds) + byte);
                af[q] = tmp.h;
            }
#pragma unroll
            for (int m = 0; m < 2; ++m)
#pragma unroll
                for (int q = 0; q < 4; ++q)
                    acc2[m][q] = __builtin_amdgcn_mfma_f32_16x16x32_f16(af[q], w2f[m][s], acc2[m][q], 0, 0, 0);
        }

#pragma unroll
        for (int m = 0; m < 2; ++m) {
            const int ch = chBase + m * 16 + l15;
#pragma unroll
            for (int q = 0; q < 4; ++q)
#pragma unroll
                for (int r = 0; r < 4; ++r) {
                    const int d = q * 16 + lg * 4 + r;
                    const long long gp = base + d;
                    if (gp < n)
                        out[gp * C + ch] = fmaxf(acc2[m][q][r], 0.f);
                }
        }
        __syncthreads();  // bar4: h reads done before next-iter staging
    }
}

// -------------------------------------------------------------------------
// Launch
// -------------------------------------------------------------------------
extern "C" void kernel_launch(void* const* d_in, const int* in_sizes, int n_in,
                              void* d_out, int out_size, void* d_ws, size_t ws_size,
                              hipStream_t stream) {
    const float* feats = (const float*)d_in[0];
    const float* W1    = (const float*)d_in[1];
    const float* b1    = (const float*)d_in[2];
    const float* W2    = (const float*)d_in[3];
    const float* b2    = (const float*)d_in[4];
    const int*   idx   = (const int*)d_in[5];
    float*       out   = (float*)d_out;

    const int n = in_sizes[5];

    // Workspace: cnt[V] int | bucket[V*64] int | pooled[V*C] f16
    int* cnt    = (int*)d_ws;
    int* bucket = cnt + V;
    __half* pooled = (__half*)(bucket + (size_t)V * BKT);

    zero_cnt<<<V / (256 * 4), 256, 0, stream>>>((int4*)cnt);
    bucket_scatter<<<(n + 255) / 256, 256, 0, stream>>>(idx, cnt, bucket, n);
    pool_bucket<<<V / 4, 256, 0, stream>>>(feats, bucket, cnt, pooled);
    mlp_mfma<<<1024, BLOCK, 0, stream>>>(feats, W1, b1, W2, b2, idx,
                                         pooled, out, n);
}

// Round 11
// 243.437 us; speedup vs baseline: 1.0966x; 1.0966x over previous
//
#include <hip/hip_runtime.h>
#include <hip/hip_fp16.h>

typedef _Float16 f16;
typedef _Float16 f16x8 __attribute__((ext_vector_type(8)));
typedef float f32x4 __attribute__((ext_vector_type(4)));

constexpr int C = 128;     // channels
constexpr int V = 65536;   // voxels
constexpr int PTS = 64;    // points per MFMA tile
constexpr int BLOCK = 256; // 4 waves
constexpr int BKT = 64;    // bucket capacity per voxel (P(overflow) ~ 1e-26)
constexpr int MLP_GRID = 512;            // 2 blocks/CU (LDS-capped)
constexpr size_t MLP_LDS = 80 * 1024;    // fstage 32K | pstage 16K | osh 16K | f 16K

union U16 { uint4 u; f16x8 h; };

// async global->LDS, 16B per lane; LDS dest = wave-uniform base + lane*16
__device__ __forceinline__ void gll16(const void* g, void* l) {
    auto gp = (const __attribute__((address_space(1))) unsigned int*)(unsigned long long)(uintptr_t)g;
    auto lp = (__attribute__((address_space(3))) unsigned int*)(unsigned int)(uintptr_t)l;
    __builtin_amdgcn_global_load_lds(gp, lp, 16, 0, 0);
}

// barrier that does NOT drain vmcnt (keeps global_load_lds in flight)
__device__ __forceinline__ void bar_nodrain() {
    asm volatile("s_waitcnt lgkmcnt(0)" ::: "memory");
    __builtin_amdgcn_s_barrier();
    asm volatile("" ::: "memory");
}

// -------------------------------------------------------------------------
// Kernel 0: zero the counters (rocclr's small fill kernel is latency-bound).
// -------------------------------------------------------------------------
__global__ void zero_cnt(int4* __restrict__ cnt) {
    const int t = blockIdx.x * blockDim.x + threadIdx.x;
    cnt[t] = make_int4(0, 0, 0, 0);
}

// -------------------------------------------------------------------------
// Kernel 1: bucket scatter — fixed-stride CSR, no scan needed.
// -------------------------------------------------------------------------
__global__ void bucket_scatter(const int* __restrict__ idx, int* __restrict__ cnt,
                               int* __restrict__ bucket, int n) {
    const int t = blockIdx.x * blockDim.x + threadIdx.x;
    if (t < n) {
        const int v = idx[t];
        const int slot = atomicAdd(&cnt[v], 1);
        if (slot < BKT) bucket[(v << 6) + slot] = t;
    }
}

// -------------------------------------------------------------------------
// Kernel 2: pooling — one wave per voxel, fp32 accumulate (4-deep ILP),
// f16 mean store.
// -------------------------------------------------------------------------
__global__ void __launch_bounds__(256)
pool_bucket(const float* __restrict__ feats, const int* __restrict__ bucket,
            const int* __restrict__ cnt, __half* __restrict__ pooled) {
    const int v = blockIdx.x * 4 + (threadIdx.x >> 6);
    const int lane = threadIdx.x & 63;
    const int e = min(cnt[v], BKT);
    const int* b = bucket + (v << 6);
    float ax = 0.f, ay = 0.f, bx = 0.f, by = 0.f;
    float cx = 0.f, cy = 0.f, dx = 0.f, dy = 0.f;
    int j = 0;
    for (; j + 4 <= e; j += 4) {
        const int p0 = b[j], p1 = b[j + 1], p2 = b[j + 2], p3 = b[j + 3];
        const float2 f0 = *reinterpret_cast<const float2*>(feats + (size_t)p0 * C + lane * 2);
        const float2 f1 = *reinterpret_cast<const float2*>(feats + (size_t)p1 * C + lane * 2);
        const float2 f2 = *reinterpret_cast<const float2*>(feats + (size_t)p2 * C + lane * 2);
        const float2 f3 = *reinterpret_cast<const float2*>(feats + (size_t)p3 * C + lane * 2);
        ax += f0.x; ay += f0.y; bx += f1.x; by += f1.y;
        cx += f2.x; cy += f2.y; dx += f3.x; dy += f3.y;
    }
    for (; j < e; ++j) {
        const int p0 = b[j];
        const float2 f0 = *reinterpret_cast<const float2*>(feats + (size_t)p0 * C + lane * 2);
        ax += f0.x; ay += f0.y;
    }
    const float rc = e ? 1.0f / (float)e : 0.f;
    *reinterpret_cast<__half2*>(pooled + (size_t)v * C + lane * 2) =
        __floats2half2_rn((ax + bx + cx + dx) * rc, (ay + by + cy + dy) * rc);
}

// -------------------------------------------------------------------------
// Kernel 3: fused gather + 2-layer MLP via f16 MFMA (16x16x32).
// Staging: global_load_lds DMA of tile t+1 (feats f32 + pooled f16) into
// granule-transposed LDS buffers, issued under tile t's compute. Zero VGPR
// cost (R10's reg-prefetch crossed the 128-reg cliff). Non-draining
// barriers keep the DMA in flight; one vmcnt(0) per tile at the top.
//   os  = feats - pooled_mean[idx]   (f16, XOR-swizzled, osh buffer)
//   h   = relu(os @ W1 + b1) * feats (h overwrites osh)
//   out = relu(h @ W2 + b2)
// -------------------------------------------------------------------------
__global__ void __launch_bounds__(BLOCK)
mlp_mfma(const float* __restrict__ feats,
         const float* __restrict__ W1g,
         const float* __restrict__ b1g,
         const float* __restrict__ W2g,
         const float* __restrict__ b2g,
         const int* __restrict__ idx,
         const __half* __restrict__ pooled,
         float* __restrict__ out,
         int n) {
    extern __shared__ char smem[];
    char* fstage = smem;             // 32 KB: [c:0..7][t]*16B  (feats f32)
    char* pstage = smem + 32768;     // 16 KB: [c:0..3][t]*16B  (pooled f16)
    char* osh    = smem + 49152;     // 16 KB f16 swizzled (os, then h)
    char* flds   = smem + 65536;     // 16 KB f16 swizzled (f)

    const int t = threadIdx.x;
    const int lane = t & 63;
    const int wv = t >> 6;
    const int l15 = lane & 15;
    const int lg = lane >> 4;
    const int chBase = 32 * wv;

    // Weight fragments in registers (B-frag: col = lane&15, k = (lane>>4)*8+j)
    const int ch0 = chBase + l15;
    const int ch1 = chBase + 16 + l15;
    f16x8 w1f[2][4], w2f[2][4];
#pragma unroll
    for (int m = 0; m < 2; ++m) {
        const int ch = (m == 0) ? ch0 : ch1;
#pragma unroll
        for (int s = 0; s < 4; ++s) {
            f16x8 a, b;
#pragma unroll
            for (int j = 0; j < 8; ++j) {
                const int k = s * 32 + lg * 8 + j;
                a[j] = (f16)W1g[k * C + ch];
                b[j] = (f16)W2g[k * C + ch];
            }
            w1f[m][s] = a;
            w2f[m][s] = b;
        }
    }
    const float b1v[2] = {b1g[ch0], b1g[ch1]};
    const float b2v[2] = {b2g[ch0], b2g[ch1]};

    const int sp = t >> 2;          // point slot 0..63
    const int sc = (t & 3) * 32;    // channel base 0/32/64/96
    const long long step = (long long)gridDim.x * PTS;
    const long long base0 = (long long)blockIdx.x * PTS;

    int vnx;  // voxel id of this thread's point in the NEXT tile
    // ---- Prologue: DMA tile 0; prefetch idx for tile 1 -------------------
    {
        const long long p = base0 + sp;
        const long long pc = (p < n) ? p : (long long)(n - 1);  // keep all lanes active
        const int v0 = idx[pc];
        const char* fs = (const char*)(feats + (size_t)pc * C + sc);
#pragma unroll
        for (int c = 0; c < 8; ++c) gll16(fs + c * 16, fstage + c * 4096 + t * 16);
        const char* ps = (const char*)(pooled + (size_t)v0 * C + sc);
#pragma unroll
        for (int c = 0; c < 4; ++c) gll16(ps + c * 16, pstage + c * 4096 + t * 16);
        const long long p1 = base0 + step + sp;
        vnx = (p1 < n) ? idx[p1] : 0;
    }

    for (long long base = base0; base < n; base += step) {
        // ---- Wait DMA, convert own stripes -> osh/f (f16, swizzled) ------
        asm volatile("s_waitcnt vmcnt(0)" ::: "memory");
        {
            const bool valid = (base + sp) < n;
            union { uint4 u[4]; f16 h[32]; } osv, fvh;
            if (valid) {
#pragma unroll
                for (int c = 0; c < 4; ++c) {
                    union { uint4 u; float f[4]; } a, b;
                    union { uint4 u; __half h[8]; } ph;
                    a.u = *reinterpret_cast<const uint4*>(fstage + (2 * c) * 4096 + t * 16);
                    b.u = *reinterpret_cast<const uint4*>(fstage + (2 * c + 1) * 4096 + t * 16);
                    ph.u = *reinterpret_cast<const uint4*>(pstage + c * 4096 + t * 16);
#pragma unroll
                    for (int j = 0; j < 4; ++j) {
                        const float f0 = a.f[j];
                        const float f1 = b.f[j];
                        osv.h[c * 8 + j]     = (f16)(f0 - __half2float(ph.h[j]));
                        osv.h[c * 8 + 4 + j] = (f16)(f1 - __half2float(ph.h[4 + j]));
                        fvh.h[c * 8 + j]     = (f16)f0;
                        fvh.h[c * 8 + 4 + j] = (f16)f1;
                    }
                }
            } else {
#pragma unroll
                for (int j = 0; j < 4; ++j) { osv.u[j] = make_uint4(0,0,0,0); fvh.u[j] = make_uint4(0,0,0,0); }
            }
#pragma unroll
            for (int u = 0; u < 4; ++u) {
                const int byte = (sp * 256 + (sc + u * 8) * 2) ^ ((sp & 7) << 4);
                *reinterpret_cast<uint4*>(osh + byte) = osv.u[u];
                *reinterpret_cast<uint4*>(flds + byte) = fvh.u[u];
            }
        }

        // ---- Issue DMA for tile t+1 (wave-private stripes; own reads done)
        if (base + step < n) {  // block-uniform guard
            const long long p = base + step + sp;
            const long long pc = (p < n) ? p : (long long)(n - 1);
            const int v = (p < n) ? vnx : 0;
            const char* fs = (const char*)(feats + (size_t)pc * C + sc);
#pragma unroll
            for (int c = 0; c < 8; ++c) gll16(fs + c * 16, fstage + c * 4096 + t * 16);
            const char* ps = (const char*)(pooled + (size_t)v * C + sc);
#pragma unroll
            for (int c = 0; c < 4; ++c) gll16(ps + c * 16, pstage + c * 4096 + t * 16);
            const long long p2 = base + 2 * step + sp;
            vnx = (p2 < n) ? idx[p2] : 0;
        }
        bar_nodrain();  // bar1: os/f staged (DMA stays in flight)

        // ---- Layer 1: acc = os @ W1 + b1 ---------------------------------
        f32x4 acc[2][4];
#pragma unroll
        for (int m = 0; m < 2; ++m)
#pragma unroll
            for (int q = 0; q < 4; ++q)
                acc[m][q] = (f32x4){b1v[m], b1v[m], b1v[m], b1v[m]};

#pragma unroll
        for (int s = 0; s < 4; ++s) {
            f16x8 af[4];
#pragma unroll
            for (int q = 0; q < 4; ++q) {
                const int p = q * 16 + l15;
                const int byte = (p * 256 + (s * 32 + lg * 8) * 2) ^ ((p & 7) << 4);
                U16 tmp;
                tmp.u = *reinterpret_cast<const uint4*>(osh + byte);
                af[q] = tmp.h;
            }
#pragma unroll
            for (int m = 0; m < 2; ++m)
#pragma unroll
                for (int q = 0; q < 4; ++q)
                    acc[m][q] = __builtin_amdgcn_mfma_f32_16x16x32_f16(af[q], w1f[m][s], acc[m][q], 0, 0, 0);
        }
        bar_nodrain();  // bar2: os reads done -> safe to overwrite with h

        // ---- h = relu(acc) * f -> osh (overwrite os) ---------------------
        // C/D layout: col = lane&15 (channel), row = (lane>>4)*4 + reg (point)
#pragma unroll
        for (int m = 0; m < 2; ++m) {
            const int ch = chBase + m * 16 + l15;
#pragma unroll
            for (int q = 0; q < 4; ++q)
#pragma unroll
                for (int r = 0; r < 4; ++r) {
                    const int d = q * 16 + lg * 4 + r;
                    const int byte = (d * 256 + ch * 2) ^ ((d & 7) << 4);
                    const float fval = (float)*reinterpret_cast<const f16*>(flds + byte);
                    const float hv = fmaxf(acc[m][q][r], 0.f) * fval;
                    *reinterpret_cast<f16*>(osh + byte) = (f16)hv;
                }
        }
        bar_nodrain();  // bar3: h ready

        // ---- Layer 2: out = relu(h @ W2 + b2) ----------------------------
        f32x4 acc2[2][4];
#pragma unroll
        for (int m = 0; m < 2; ++m)
#pragma unroll
            for (int q = 0; q < 4; ++q)
                acc2[m][q] = (f32x4){b2v[m], b2v[m], b2v[m], b2v[m]};

#pragma unroll
        for (int s = 0; s < 4; ++s) {
            f16x8 af[4];
#pragma unroll
            for (int q = 0; q < 4; ++q) {
                const int p = q * 16 + l15;
                const int byte = (p * 256 + (s * 32 + lg * 8) * 2) ^ ((p & 7) << 4);
                U16 tmp;
                tmp.u = *reinterpret_cast<const uint4*>(osh + byte);
                af[q] = tmp.h;
            }
#pragma unroll
            for (int m = 0; m < 2; ++m)
#pragma unroll
                for (int q = 0; q < 4; ++q)
                    acc2[m][q] = __builtin_amdgcn_mfma_f32_16x16x32_f16(af[q], w2f[m][s], acc2[m][q], 0, 0, 0);
        }

#pragma unroll
        for (int m = 0; m < 2; ++m) {
            const int ch = chBase + m * 16 + l15;
#pragma unroll
            for (int q = 0; q < 4; ++q)
#pragma unroll
                for (int r = 0; r < 4; ++r) {
                    const int d = q * 16 + lg * 4 + r;
                    const long long gp = base + d;
                    if (gp < n)
                        out[gp * C + ch] = fmaxf(acc2[m][q][r], 0.f);
                }
        }
        bar_nodrain();  // bar4: h reads done before next stage-convert
    }
}

// -------------------------------------------------------------------------
// Launch
// -------------------------------------------------------------------------
extern "C" void kernel_launch(void* const* d_in, const int* in_sizes, int n_in,
                              void* d_out, int out_size, void* d_ws, size_t ws_size,
                              hipStream_t stream) {
    const float* feats = (const float*)d_in[0];
    const float* W1    = (const float*)d_in[1];
    const float* b1    = (const float*)d_in[2];
    const float* W2    = (const float*)d_in[3];
    const float* b2    = (const float*)d_in[4];
    const int*   idx   = (const int*)d_in[5];
    float*       out   = (float*)d_out;

    const int n = in_sizes[5];

    // Workspace: cnt[V] int | bucket[V*64] int | pooled[V*C] f16
    int* cnt    = (int*)d_ws;
    int* bucket = cnt + V;
    __half* pooled = (__half*)(bucket + (size_t)V * BKT);

    zero_cnt<<<V / (256 * 4), 256, 0, stream>>>((int4*)cnt);
    bucket_scatter<<<(n + 255) / 256, 256, 0, stream>>>(idx, cnt, bucket, n);
    pool_bucket<<<V / 4, 256, 0, stream>>>(feats, bucket, cnt, pooled);

    hipFuncSetAttribute((const void*)mlp_mfma,
                        hipFuncAttributeMaxDynamicSharedMemorySize,
                        (int)MLP_LDS);
    mlp_mfma<<<MLP_GRID, BLOCK, MLP_LDS, stream>>>(feats, W1, b1, W2, b2, idx,
                                                   pooled, out, n);
}